// Round 2
// 157.973 us; speedup vs baseline: 1.8355x; 1.8355x over previous
//
#include <hip/hip_runtime.h>

// Problem: out[b] = weight[layer_ids[b]] @ z[b] + bias[layer_ids[b]]
// All fp32 (layer_ids int32). z[4096,1024], weight[16,1024,1024],
// bias[16,1024], out[4096,1024].
//
// R7 (= R6 + type fix): route the GEMM through the matrix pipe. fp32 operands
// are split into f16 hi/lo pairs (a = ah + al) staged in LDS; each 16x16x32
// fragment pair does 3 MFMA passes (ah*bh + ah*bl + al*bh) -> fp32-equivalent
// accuracy (error ~2^-20 rel, << the 0.0156 ref-vs-fp32 baseline divergence).
// Structure: counting-sort grouping (unchanged) + grouped MFMA GEMM,
// 128x128 tile, BK=32, 4 waves (2x2, 64x64 each), double-buffered LDS,
// XOR-swizzled (8B-cell) rows for conflict-free ds_read_b128,
// XCD-pinned layer placement (bid%8 -> XCD, 2 layers/XCD).

#define HDIM 1024
#define LNUM 16
#define BTOT 4096

constexpr int BM = 128, BN = 128, BK = 32;
constexpr int NT = HDIM / BK;  // 32 K-steps

constexpr int LROW = 128;      // LDS bytes per tile row: [32 hi f16 | 32 lo f16]
constexpr int AOFF = 0;        // A tile: 128 rows * 128B = 16KB
constexpr int BOFF = 16384;    // B tile: 16KB
constexpr int BUFSZ = 32768;   // one double-buffer half

typedef __attribute__((ext_vector_type(4))) float floatx4;
typedef __attribute__((ext_vector_type(2))) __fp16 cvt16x2;   // cvt_pkrtz result
typedef __attribute__((ext_vector_type(8))) _Float16 f16x8;   // MFMA fragment
typedef __attribute__((ext_vector_type(2))) unsigned int uintx2;

// ---------------------------------------------------------------------------
// Kernel 1: group batch rows by layer (counting sort). Single block.
// ---------------------------------------------------------------------------
__global__ void group_kernel(const int* __restrict__ layer_ids,
                             int* __restrict__ perm,
                             int* __restrict__ offsets) {
    __shared__ int cnt[LNUM];
    __shared__ int base[LNUM];
    const int t = threadIdx.x;
    if (t < LNUM) cnt[t] = 0;
    __syncthreads();
    for (int b = t; b < BTOT; b += 256)
        atomicAdd(&cnt[layer_ids[b] & (LNUM - 1)], 1);
    __syncthreads();
    if (t == 0) {
        int acc = 0;
        for (int l = 0; l < LNUM; ++l) {
            base[l] = acc;
            offsets[l] = acc;
            acc += cnt[l];
        }
        offsets[LNUM] = acc;
    }
    __syncthreads();
    if (t < LNUM) cnt[t] = 0;
    __syncthreads();
    for (int b = t; b < BTOT; b += 256) {
        int l = layer_ids[b] & (LNUM - 1);
        int p = base[l] + atomicAdd(&cnt[l], 1);
        perm[p] = b;
    }
}

// ---------------------------------------------------------------------------
// Helper: split a floatx4 into packed hi/lo f16 words.
// ---------------------------------------------------------------------------
__device__ __forceinline__ void split4(floatx4 v, uintx2& hw, uintx2& lw) {
    cvt16x2 h01 = __builtin_amdgcn_cvt_pkrtz(v[0], v[1]);
    cvt16x2 h23 = __builtin_amdgcn_cvt_pkrtz(v[2], v[3]);
    cvt16x2 l01 = __builtin_amdgcn_cvt_pkrtz(v[0] - (float)h01[0],
                                             v[1] - (float)h01[1]);
    cvt16x2 l23 = __builtin_amdgcn_cvt_pkrtz(v[2] - (float)h23[0],
                                             v[3] - (float)h23[1]);
    hw[0] = __builtin_bit_cast(unsigned int, h01);
    hw[1] = __builtin_bit_cast(unsigned int, h23);
    lw[0] = __builtin_bit_cast(unsigned int, l01);
    lw[1] = __builtin_bit_cast(unsigned int, l23);
}

// ---------------------------------------------------------------------------
// Kernel 2: grouped split-f16 MFMA GEMM.
// out[perm[off+m]][n] = sum_k z[perm[off+m]][k] * w[l][n][k] + bias[l][n]
// ---------------------------------------------------------------------------
__global__ __launch_bounds__(256, 2) void grouped_mfma_kernel(
    const float* __restrict__ z,
    const float* __restrict__ weight,
    const float* __restrict__ bias,
    const int* __restrict__ perm,
    const int* __restrict__ offsets,
    float* __restrict__ out) {

    // XCD-pinned decode: bid%8 selects XCD (m09 round-robin); give each XCD
    // layers {xcd, xcd+8} so each layer's 4MB weight tile stays in one L2.
    const int bid  = blockIdx.x;
    const int xcd  = bid & 7;
    const int slot = bid >> 3;          // 0..511
    const int l    = xcd + ((slot >> 8) << 3);   // 0..15
    const int rem  = slot & 255;
    const int my   = rem >> 3;          // m-block 0..31 (covers cnt<=4096)
    const int nx   = rem & 7;           // n-block 0..7

    const int off = offsets[l];
    const int cnt = offsets[l + 1] - off;
    const int m0 = my * BM;
    if (m0 >= cnt) return;  // dead tile, uniform exit (before any barrier)
    const int n0 = nx * BN;

    __shared__ __align__(16) unsigned char sm[2][BUFSZ];

    const int tid  = threadIdx.x;
    const int lane = tid & 63;
    const int w    = tid >> 6;          // wave 0..3
    const int wm   = w & 1;             // wave m-slot (rows wm*64..+63)
    const int wn   = w >> 1;            // wave n-slot (cols wn*64..+63)

    // ---- staging maps: thread t loads 4-float chunks; rows rb+32p ----
    const int kq  = tid & 7;            // which 16B chunk of the 32-k slab
    const int rb  = tid >> 3;           // row 0..31 within each 32-row group
    const int swz = (rb & 7) << 1;      // 8B-cell XOR swizzle

    const float* aPtr[4];
    const float* bPtr[4];
#pragma unroll
    for (int p = 0; p < 4; ++p) {
        int gm = m0 + rb + 32 * p;
        if (gm > cnt - 1) gm = cnt - 1;          // clamp (stores guarded)
        aPtr[p] = z + (size_t)perm[off + gm] * HDIM + kq * 4;
        bPtr[p] = weight + (size_t)l * HDIM * HDIM
                         + (size_t)(n0 + rb + 32 * p) * HDIM + kq * 4;
    }
    // LDS write byte offsets (8B cells; hi cell = kq, lo cell = 8+kq)
    const int wA_hi = AOFF + rb * LROW + ((kq ^ swz) << 3);
    const int wA_lo = AOFF + rb * LROW + (((8 + kq) ^ swz) << 3);
    const int wB_hi = BOFF + rb * LROW + ((kq ^ swz) << 3);
    const int wB_lo = BOFF + rb * LROW + (((8 + kq) ^ swz) << 3);

    // ---- fragment read maps (16B slots; slot s=lane>>4 hi, 4+s lo) ----
    const int lr = lane & 15;
    const int ks = lane >> 4;
    const int rA = wm * 64 + lr;
    const int rB = wn * 64 + lr;
    const int rdA_hi = AOFF + rA * LROW + ((ks ^ (lr & 7)) << 4);
    const int rdA_lo = AOFF + rA * LROW + (((4 + ks) ^ (lr & 7)) << 4);
    const int rdB_hi = BOFF + rB * LROW + ((ks ^ (lr & 7)) << 4);
    const int rdB_lo = BOFF + rB * LROW + (((4 + ks) ^ (lr & 7)) << 4);

    floatx4 acc[4][4] = {};
    floatx4 av[4], bv[4];

    auto loadT = [&](int k0) {
#pragma unroll
        for (int p = 0; p < 4; ++p) {
            av[p] = *(const floatx4*)(aPtr[p] + k0);
            bv[p] = *(const floatx4*)(bPtr[p] + k0);
        }
    };

    auto stageT = [&](unsigned char* buf) {
#pragma unroll
        for (int p = 0; p < 4; ++p) {
            uintx2 hw, lw;
            split4(av[p], hw, lw);
            *(uintx2*)(buf + wA_hi + p * 4096) = hw;
            *(uintx2*)(buf + wA_lo + p * 4096) = lw;
            split4(bv[p], hw, lw);
            *(uintx2*)(buf + wB_hi + p * 4096) = hw;
            *(uintx2*)(buf + wB_lo + p * 4096) = lw;
        }
    };

    auto compute = [&](const unsigned char* buf) {
        f16x8 ah[4], al[4], bh[4], bl[4];
#pragma unroll
        for (int i = 0; i < 4; ++i) {
            ah[i] = *(const f16x8*)(buf + rdA_hi + i * 2048);
            al[i] = *(const f16x8*)(buf + rdA_lo + i * 2048);
            bh[i] = *(const f16x8*)(buf + rdB_hi + i * 2048);
            bl[i] = *(const f16x8*)(buf + rdB_lo + i * 2048);
        }
#pragma unroll
        for (int i = 0; i < 4; ++i)
#pragma unroll
            for (int j = 0; j < 4; ++j) {
                acc[i][j] = __builtin_amdgcn_mfma_f32_16x16x32_f16(
                    ah[i], bh[j], acc[i][j], 0, 0, 0);
                acc[i][j] = __builtin_amdgcn_mfma_f32_16x16x32_f16(
                    ah[i], bl[j], acc[i][j], 0, 0, 0);
                acc[i][j] = __builtin_amdgcn_mfma_f32_16x16x32_f16(
                    al[i], bh[j], acc[i][j], 0, 0, 0);
            }
    };

    // Prologue: stage K-step 0 into buf 0.
    loadT(0);
    stageT(sm[0]);
    __syncthreads();

#pragma unroll 1
    for (int t2 = 0; t2 < NT; t2 += 2) {
        // even step: compute buf0, stage t2+1 -> buf1 (loads issued early)
        loadT((t2 + 1) * BK);
        compute(sm[0]);
        stageT(sm[1]);
        __syncthreads();
        // odd step: compute buf1, stage t2+2 -> buf0
        if (t2 + 2 < NT) {
            loadT((t2 + 2) * BK);
            compute(sm[1]);
            stageT(sm[0]);
            __syncthreads();
        } else {
            compute(sm[1]);
        }
    }

    // Epilogue: C/D layout col=lane&15, row=(lane>>4)*4+reg (m89-verified).
    const int colBase = n0 + wn * 64 + lr;
    float bb[4];
#pragma unroll
    for (int j = 0; j < 4; ++j) bb[j] = bias[l * HDIM + colBase + j * 16];

    const int rq = lane >> 4;
#pragma unroll
    for (int i = 0; i < 4; ++i) {
#pragma unroll
        for (int v = 0; v < 4; ++v) {
            int gm = m0 + wm * 64 + i * 16 + rq * 4 + v;
            if (gm < cnt) {
                float* o = out + (size_t)perm[off + gm] * HDIM + colBase;
#pragma unroll
                for (int j = 0; j < 4; ++j) o[j * 16] = acc[i][j][v] + bb[j];
            }
        }
    }
}

extern "C" void kernel_launch(void* const* d_in, const int* in_sizes, int n_in,
                              void* d_out, int out_size, void* d_ws, size_t ws_size,
                              hipStream_t stream) {
    // Order-proof pointer resolution (validated in R4: sizes disambiguate).
    const float* z = nullptr;
    const int* layer_ids = nullptr;
    const float* weight = nullptr;
    const float* bias = nullptr;
    for (int i = 0; i < n_in; ++i) {
        switch (in_sizes[i]) {
            case BTOT * HDIM:        z = (const float*)d_in[i]; break;
            case BTOT:               layer_ids = (const int*)d_in[i]; break;
            case LNUM * HDIM * HDIM: weight = (const float*)d_in[i]; break;
            case LNUM * HDIM:        bias = (const float*)d_in[i]; break;
        }
    }
    float* out = (float*)d_out;

    int* perm = (int*)d_ws;       // 4096 ints
    int* offsets = perm + BTOT;   // 17 ints

    group_kernel<<<1, 256, 0, stream>>>(layer_ids, perm, offsets);

    // Flat 1-D grid: 8 XCD slots x 2 layers x 32 m-blocks x 8 n-blocks = 4096.
    grouped_mfma_kernel<<<dim3(4096), 256, 0, stream>>>(z, weight, bias, perm,
                                                        offsets, out);
}

// Round 3
// 146.061 us; speedup vs baseline: 1.9852x; 1.0816x over previous
//
#include <hip/hip_runtime.h>

// Problem: out[b] = weight[layer_ids[b]] @ z[b] + bias[layer_ids[b]]
// All fp32 (layer_ids int32). z[4096,1024], weight[16,1024,1024],
// bias[16,1024], out[4096,1024].
//
// R8: single-dispatch fused kernel.
//  - Grouping fused into the GEMM: each block scans layer_ids (16 KB, L2)
//    with mask+popcount+wave-scan and builds its 64-row perm tile in LDS.
//    Removes the serial single-block group_kernel (~90 us of the R7 total).
//  - Tile 64x128 (was 128x128): ~576 live blocks (~2.3/CU), LDS 48 KB dbuf
//    -> 3 blocks/CU capacity, launch_bounds(256,3). Wave tile 32x64,
//    acc[2][4] -> ~140 VGPR working set (R7's 128x128 needed ~160 vs the
//    allocator's 100 -> serialized chains).
//  - Split-f16 3-pass MFMA core, XOR-swizzled LDS, double-buffered,
//    issue-early/stage-late (unchanged from R7; absmax-verified).

#define HDIM 1024
#define LNUM 16
#define BTOT 4096

constexpr int BM = 64, BN = 128, BK = 32;
constexpr int NT = HDIM / BK;   // 32 K-steps
constexpr int MSLOTS = 8;       // m-tiles per layer in grid (strip-mined past)

constexpr int LROW = 128;       // LDS bytes per tile row: [32 hi f16 | 32 lo f16]
constexpr int AOFF = 0;         // A tile: 64 rows * 128B = 8 KB
constexpr int BOFF = 8192;      // B tile: 128 rows * 128B = 16 KB
constexpr int BUFSZ = 24576;    // one double-buffer half

typedef __attribute__((ext_vector_type(4))) float floatx4;
typedef __attribute__((ext_vector_type(2))) __fp16 cvt16x2;   // cvt_pkrtz result
typedef __attribute__((ext_vector_type(8))) _Float16 f16x8;   // MFMA fragment
typedef __attribute__((ext_vector_type(2))) unsigned int uintx2;

// Split a floatx4 into packed hi/lo f16 words (a = ah + al exactly in f16 pair).
__device__ __forceinline__ void split4(floatx4 v, uintx2& hw, uintx2& lw) {
    cvt16x2 h01 = __builtin_amdgcn_cvt_pkrtz(v[0], v[1]);
    cvt16x2 h23 = __builtin_amdgcn_cvt_pkrtz(v[2], v[3]);
    cvt16x2 l01 = __builtin_amdgcn_cvt_pkrtz(v[0] - (float)h01[0],
                                             v[1] - (float)h01[1]);
    cvt16x2 l23 = __builtin_amdgcn_cvt_pkrtz(v[2] - (float)h23[0],
                                             v[3] - (float)h23[1]);
    hw[0] = __builtin_bit_cast(unsigned int, h01);
    hw[1] = __builtin_bit_cast(unsigned int, h23);
    lw[0] = __builtin_bit_cast(unsigned int, l01);
    lw[1] = __builtin_bit_cast(unsigned int, l23);
}

__global__ __launch_bounds__(256, 3) void fused_grouped_mfma_kernel(
    const float* __restrict__ z,
    const int* __restrict__ layer_ids,
    const float* __restrict__ weight,
    const float* __restrict__ bias,
    float* __restrict__ out) {

    // Grid: 1024 blocks = 8 XCD x {2 layer-halves x 8 m-slots x 8 n-blocks}.
    // bid&7 pins layer l to XCD (HW round-robins consecutive bids across XCDs)
    // so each layer's 4MB weight panel lives in ~one L2.
    const int bid  = blockIdx.x;
    const int xcd  = bid & 7;
    const int slot = bid >> 3;                 // 0..127
    const int l    = xcd + ((slot >> 6) << 3); // 0..15
    const int rem  = slot & 63;
    const int my   = rem >> 3;                 // m-slot 0..7
    const int nx   = rem & 7;                  // n-block 0..7
    const int n0   = nx * BN;

    const int tid  = threadIdx.x;
    const int lane = tid & 63;
    const int w    = tid >> 6;                 // wave 0..3
    const int wm   = w & 1;                    // wave m-slot (rows wm*32..+31)
    const int wn   = w >> 1;                   // wave n-slot (cols wn*64..+63)

    __shared__ __align__(16) unsigned char sm[2][BUFSZ];
    __shared__ int permTile[BM];
    __shared__ int waveSums[4];

    // ---- fused grouping scan: rank of each matching b among layer-l rows ----
    // Thread t owns b in [16t, 16t+16); mask bit q <=> layer_ids[16t+q]==l.
    const int4* lid4 = (const int4*)layer_ids;
    unsigned mask = 0;
#pragma unroll
    for (int q = 0; q < 4; ++q) {
        int4 v = lid4[tid * 4 + q];
        mask |= (unsigned)(v.x == l) << (4 * q)
             |  (unsigned)(v.y == l) << (4 * q + 1)
             |  (unsigned)(v.z == l) << (4 * q + 2)
             |  (unsigned)(v.w == l) << (4 * q + 3);
    }
    const int ct = __popc(mask);
    int x = ct;                                // wave-inclusive scan of ct
#pragma unroll
    for (int o = 1; o < 64; o <<= 1) {
        int v = __shfl_up(x, o);
        if (lane >= o) x += v;
    }
    if (lane == 63) waveSums[w] = x;
    __syncthreads();
    int waveBase = 0, cnt = 0;
#pragma unroll
    for (int w2 = 0; w2 < 4; ++w2) {
        int s = waveSums[w2];
        if (w2 < w) waveBase += s;
        cnt += s;
    }
    const int et = waveBase + x - ct;          // exclusive rank of 1st match

    // ---- staging / fragment maps (constant across m0 iterations) ----
    const int kq  = tid & 7;                   // 16B f32 chunk within 32-k slab
    const int rb  = tid >> 3;                  // staging row 0..31 (+32p)
    const int swz = (rb & 7) << 1;             // 8B-cell XOR swizzle
    const int wA_hi = AOFF + rb * LROW + ((kq ^ swz) << 3);
    const int wA_lo = AOFF + rb * LROW + (((8 + kq) ^ swz) << 3);
    const int wB_hi = BOFF + rb * LROW + ((kq ^ swz) << 3);
    const int wB_lo = BOFF + rb * LROW + (((8 + kq) ^ swz) << 3);

    const int lr = lane & 15;
    const int ks = lane >> 4;
    const int rdA_hi = AOFF + (wm * 32 + lr) * LROW + ((ks ^ (lr & 7)) << 4);
    const int rdA_lo = AOFF + (wm * 32 + lr) * LROW + (((4 + ks) ^ (lr & 7)) << 4);
    const int rdB_hi = BOFF + (wn * 64 + lr) * LROW + ((ks ^ (lr & 7)) << 4);
    const int rdB_lo = BOFF + (wn * 64 + lr) * LROW + (((4 + ks) ^ (lr & 7)) << 4);

    const float* wBase = weight + (size_t)l * HDIM * HDIM;
    const int colBase = n0 + wn * 64 + lr;
    float bb[4];
#pragma unroll
    for (int j = 0; j < 4; ++j) bb[j] = bias[l * HDIM + colBase + j * 16];

    // ---- strip-mine m0 (single iteration for cnt <= 512, the normal case) ----
    for (int m0 = my * BM; m0 < cnt; m0 += MSLOTS * BM) {
        __syncthreads();                       // LDS reuse + permTile guard
        {
            unsigned m2 = mask;
            int r = et;
            while (m2) {
                int p = __ffs(m2) - 1;
                m2 &= m2 - 1;
                unsigned rr = (unsigned)(r - m0);
                if (rr < (unsigned)BM) permTile[rr] = tid * 16 + p;
                ++r;
            }
        }
        __syncthreads();

        const float* aPtr[2];
        const float* bPtr[4];
#pragma unroll
        for (int p = 0; p < 2; ++p) {
            int gm = rb + 32 * p;              // tile-local row
            if (gm > cnt - 1 - m0) gm = cnt - 1 - m0;   // clamp (stores guarded)
            aPtr[p] = z + (size_t)permTile[gm] * HDIM + kq * 4;
        }
#pragma unroll
        for (int p = 0; p < 4; ++p)
            bPtr[p] = wBase + (size_t)(n0 + rb + 32 * p) * HDIM + kq * 4;

        floatx4 acc[2][4] = {};
        floatx4 av[2], bv[4];

        auto loadT = [&](int k0) {
#pragma unroll
            for (int p = 0; p < 2; ++p) av[p] = *(const floatx4*)(aPtr[p] + k0);
#pragma unroll
            for (int p = 0; p < 4; ++p) bv[p] = *(const floatx4*)(bPtr[p] + k0);
        };

        auto stageT = [&](unsigned char* buf) {
            uintx2 hw, lw;
#pragma unroll
            for (int p = 0; p < 2; ++p) {
                split4(av[p], hw, lw);
                *(uintx2*)(buf + wA_hi + p * 4096) = hw;
                *(uintx2*)(buf + wA_lo + p * 4096) = lw;
            }
#pragma unroll
            for (int p = 0; p < 4; ++p) {
                split4(bv[p], hw, lw);
                *(uintx2*)(buf + wB_hi + p * 4096) = hw;
                *(uintx2*)(buf + wB_lo + p * 4096) = lw;
            }
        };

        auto compute = [&](const unsigned char* buf) {
            f16x8 ah[2], al[2], bh[4], bl[4];
#pragma unroll
            for (int i = 0; i < 2; ++i) {
                ah[i] = *(const f16x8*)(buf + rdA_hi + i * 2048);
                al[i] = *(const f16x8*)(buf + rdA_lo + i * 2048);
            }
#pragma unroll
            for (int j = 0; j < 4; ++j) {
                bh[j] = *(const f16x8*)(buf + rdB_hi + j * 2048);
                bl[j] = *(const f16x8*)(buf + rdB_lo + j * 2048);
            }
#pragma unroll
            for (int i = 0; i < 2; ++i)
#pragma unroll
                for (int j = 0; j < 4; ++j) {
                    acc[i][j] = __builtin_amdgcn_mfma_f32_16x16x32_f16(
                        ah[i], bh[j], acc[i][j], 0, 0, 0);
                    acc[i][j] = __builtin_amdgcn_mfma_f32_16x16x32_f16(
                        ah[i], bl[j], acc[i][j], 0, 0, 0);
                    acc[i][j] = __builtin_amdgcn_mfma_f32_16x16x32_f16(
                        al[i], bh[j], acc[i][j], 0, 0, 0);
                }
        };

        // Prologue: stage K-step 0 into buf 0.
        loadT(0);
        stageT(sm[0]);
        __syncthreads();

#pragma unroll 1
        for (int t2 = 0; t2 < NT; t2 += 2) {
            loadT((t2 + 1) * BK);              // issue early (T14)
            compute(sm[0]);
            stageT(sm[1]);
            __syncthreads();
            if (t2 + 2 < NT) {
                loadT((t2 + 2) * BK);
                compute(sm[1]);
                stageT(sm[0]);
                __syncthreads();
            } else {
                compute(sm[1]);
            }
        }

        // Epilogue: C/D layout col=lane&15, row=(lane>>4)*4+reg (m89-verified).
        const int rq = lane >> 4;
#pragma unroll
        for (int i = 0; i < 2; ++i) {
#pragma unroll
            for (int v = 0; v < 4; ++v) {
                int gm = wm * 32 + i * 16 + rq * 4 + v;   // tile-local row
                if (m0 + gm < cnt) {
                    float* o = out + (size_t)permTile[gm] * HDIM + colBase;
#pragma unroll
                    for (int j = 0; j < 4; ++j) o[j * 16] = acc[i][j][v] + bb[j];
                }
            }
        }
    }
}

extern "C" void kernel_launch(void* const* d_in, const int* in_sizes, int n_in,
                              void* d_out, int out_size, void* d_ws, size_t ws_size,
                              hipStream_t stream) {
    // Order-proof pointer resolution (sizes disambiguate).
    const float* z = nullptr;
    const int* layer_ids = nullptr;
    const float* weight = nullptr;
    const float* bias = nullptr;
    for (int i = 0; i < n_in; ++i) {
        switch (in_sizes[i]) {
            case BTOT * HDIM:        z = (const float*)d_in[i]; break;
            case BTOT:               layer_ids = (const int*)d_in[i]; break;
            case LNUM * HDIM * HDIM: weight = (const float*)d_in[i]; break;
            case LNUM * HDIM:        bias = (const float*)d_in[i]; break;
        }
    }
    float* out = (float*)d_out;

    // Single dispatch: 8 XCD x 2 layer-halves x 8 m-slots x 8 n-blocks = 1024.
    fused_grouped_mfma_kernel<<<dim3(1024), 256, 0, stream>>>(
        z, layer_ids, weight, bias, out);
}